// Round 5
// baseline (203.471 us; speedup 1.0000x reference)
//
#include <hip/hip_runtime.h>
#include <stdint.h>

// ---------- types ----------
typedef __bf16    bf16x8 __attribute__((ext_vector_type(8)));
typedef float     f32x4  __attribute__((ext_vector_type(4)));
typedef uint32_t  u32x4  __attribute__((ext_vector_type(4)));

#define MFMA(a,b,c) __builtin_amdgcn_mfma_f32_16x16x32_bf16((a),(b),(c),0,0,0)

// ---------- persistent device scratch (bf16 internal pipeline) ----------
__device__ __align__(16) uint16_t g_y [8*64*64*256];
__device__ __align__(16) uint16_t g_wpk[393216];

#define WQF 0
#define WKF 65536
#define WVF 131072
#define WCF 196608
#define W1F 262144
#define W2F 294912
#define WPF 327680

static __device__ __forceinline__ float b2f(uint32_t u){ return __builtin_bit_cast(float, u<<16); }
static __device__ __forceinline__ float b2fh(uint32_t u){ return __builtin_bit_cast(float, u & 0xffff0000u); }
static __device__ __forceinline__ uint32_t f2b(float f){
  uint32_t x = __builtin_bit_cast(uint32_t, f);
  return (x + 0x7fffu + ((x>>16)&1u)) >> 16;   // RNE bf16
}

// ---------- kernel 0: repack fp32 weights into bf16 B-fragment-major layout ----------
__global__ __launch_bounds__(256) void kpack(const float* __restrict__ Wqkv,
    const float* __restrict__ W1, const float* __restrict__ W2,
    const float* __restrict__ Wp){
  int idx = blockIdx.x*256 + threadIdx.x;
  int j = idx & 7, lane = (idx>>3)&63;
  int n16 = lane & 15, q4 = lane>>4;
  float v;
  if (idx < 262144){                 // q,k,v,chans from interleaved W_qkv (row o = 4c+t)
    int t = idx >> 16, l = idx & 65535;
    int s = (l>>9)&7, nt = l>>12;
    v = Wqkv[(4*(nt*16+n16) + t)*256 + s*32 + q4*8 + j];
  } else if (idx < 294912){          // W1 [128][256]
    int l = idx - 262144;
    int s = (l>>9)&7, nt = l>>12;
    v = W1[(nt*16+n16)*256 + s*32 + q4*8 + j];
  } else if (idx < 327680){          // W2 [256][128], S=4
    int l = idx - 294912;
    int s = (l>>9)&3, nt = l>>11;
    v = W2[(nt*16+n16)*128 + s*32 + q4*8 + j];
  } else {                           // Wp [256][256]
    int l = idx - 327680;
    int s = (l>>9)&7, nt = l>>12;
    v = Wp[(nt*16+n16)*256 + s*32 + q4*8 + j];
  }
  g_wpk[idx] = (uint16_t)f2b(v);
}

// ---------- kernel 1: 3x3 avg pool + NCHW->[pix][C], targeted pad zeroing ----------
__global__ __launch_bounds__(512) void kpool(const float* __restrict__ x){
  __shared__ __align__(16) uint16_t sm[3*256*82];
  uint32_t* smw = (uint32_t*)sm;
  int t = threadIdx.x;
  int b = blockIdx.x >> 6, h = blockIdx.x & 63;
  for (int i=t; i<768; i+=512){
    int base = i*41;
    smw[base+3]  = 0;
    smw[base+36] = 0;
  }
  if (h==0 || h==63){
    int hh = (h==0) ? 0 : 2;
    for (int i=t; i<10496; i+=512) smw[hh*10496 + i] = 0;
  }
  #pragma unroll
  for (int i=0;i<24;i++){
    int id = t + 512*i;
    int w4 = id&15, c = (id>>4)&255, hh = id>>12;
    int gy = h - 1 + hh;
    if ((unsigned)gy < 64u){
      f32x4 ld = *(const f32x4*)&x[(((b*256+c)*64+gy)*64) + w4*4];
      int wb = (((hh*256+c)*82 + 8 + w4*4) >> 1);
      smw[wb+0] = f2b(ld[0]) | (f2b(ld[1])<<16);
      smw[wb+1] = f2b(ld[2]) | (f2b(ld[3])<<16);
    }
  }
  __syncthreads();
  int c = t & 255, wsel = t >> 8;
  int r0 = c*82, r1 = r0 + 256*82, r2 = r1 + 256*82;
  int w0 = wsel*32;
  float csp = b2f(sm[r0+w0+7]) + b2f(sm[r1+w0+7]) + b2f(sm[r2+w0+7]);
  float csc = b2f(sm[r0+w0+8]) + b2f(sm[r1+w0+8]) + b2f(sm[r2+w0+8]);
  uint16_t* dst = g_y + ((b*64+h)*64)*256 + c;
  for (int j2=0;j2<32;j2++){
    int w = w0 + j2;
    float csn = b2f(sm[r0+w+9]) + b2f(sm[r1+w+9]) + b2f(sm[r2+w+9]);
    float yv = (csp + csc + csn) * (1.0f/9.0f);
    dst[w*256] = (uint16_t)f2b(yv);
    csp = csc; csc = csn;
  }
}

// ---------- kernel 2: fused everything, 1024 threads (16 waves, 4/SIMD) ----------
#define YSTR 264
#define HSTR 136
#define YS 0        // 100 x 264
#define QS 26400    // 64 x 136
#define KS 35104    // 100 x 136
#define VS 48704    // 100 x 136  (end 62304 u16 = 124.6 KB)
#define MCH 0       // 64 x 264  over dead Y rows 0..63
#define MHS 16896   // 64 x 136  over dead Y rows 64..96
#define MAO 26400   // 64 x 264  over dead Q/K
__global__ __launch_bounds__(1024,4) void kattn(const float* __restrict__ bqkv,
    const float* __restrict__ b1, const float* __restrict__ b2v,
    const float* __restrict__ bp, float* __restrict__ out){
  __shared__ __align__(16) uint16_t sm[62304];   // 124.6 KB
  int t = threadIdx.x;
  int lane = t & 63, wave = t >> 6;
  int n16 = lane & 15, quad = lane >> 4;
  int bid = blockIdx.x;
  int bb = bid>>6, tyhi=(bid>>4)&3, txl=(bid>>3)&1, tylo=(bid>>2)&1, txp=bid&3;
  int ty = tyhi*2+tylo, tx = txp*2+txl;

  uint32_t opk[2][8];   // packed attention output (waves 0-7)
  uint32_t chp[16];     // packed chans output (waves 8-15)

  // --- phase 1: load 10x10 y-halo (zero outside image) ---
  #pragma unroll
  for (int i=0;i<4;i++){
    int id = t + 1024*i;
    if (id < 3200){
      int hp = id >> 5, c8 = id & 31;
      int py = hp/10, px = hp - py*10;
      int gy = ty*8 + py - 1, gx = tx*8 + px - 1;
      u32x4 ld = {0,0,0,0};
      if ((unsigned)gy<64u && (unsigned)gx<64u)
        ld = *(const u32x4*)&g_y[((bb*64+gy)*64+gx)*256 + c8*8];
      *(u32x4*)&sm[hp*YSTR + c8*8] = ld;
    }
  }
  __syncthreads();

  #pragma unroll
  for (int hf=0; hf<2; hf++){
    // ---- phase 2: fused q + k/v GEMMs ----
    {
      int ntg = wave & 7;
      int ntgg = hf*8 + ntg;
      bool isK = wave < 8;
      int colB = ntg*16;
      // k or v: M=112 halo (clamped), N=16
      {
        bf16x8 Bx[8];
        const uint16_t* wb = &g_wpk[(isK?WKF:WVF)];
        #pragma unroll
        for (int s=0;s<8;s++) Bx[s] = *(const bf16x8*)&wb[((ntgg*8+s)*64+lane)*8];
        float bx = bqkv[4*(ntgg*16+n16) + (isK?1:2)];
        int base = isK ? KS : VS;
        #pragma unroll
        for (int mt=0; mt<7; mt++){
          f32x4 a = {0.f,0.f,0.f,0.f};
          int m = mt*16 + n16;
          int mr = (m < 100) ? m : 99;
          #pragma unroll
          for (int s=0;s<8;s++){
            bf16x8 A = *(const bf16x8*)&sm[YS + mr*YSTR + s*32 + quad*8];
            a = MFMA(A, Bx[s], a);
          }
          #pragma unroll
          for (int r=0;r<4;r++){
            int row = mt*16 + quad*4 + r;
            if (row < 100){
              int py = row/10, px = row - py*10;
              int gy = ty*8 + py - 1, gx = tx*8 + px - 1;
              bool ok = ((unsigned)gy<64u) && ((unsigned)gx<64u);
              sm[base + row*HSTR + colB + n16] = (uint16_t)f2b(ok ? a[r]+bx : 0.f);
            }
          }
        }
      }
      // q: 2 mt per wave (waves<8: rows 0-31, waves>=8: rows 32-63)
      {
        bf16x8 Bq[8];
        #pragma unroll
        for (int s=0;s<8;s++) Bq[s] = *(const bf16x8*)&g_wpk[WQF + ((ntgg*8+s)*64+lane)*8];
        float bq = bqkv[4*(ntgg*16+n16) + 0];
        int mt0 = isK ? 0 : 2;
        #pragma unroll
        for (int mi=0; mi<2; mi++){
          int mt = mt0 + mi;
          f32x4 a = {0.f,0.f,0.f,0.f};
          int m = mt*16 + n16;
          int hrow = 10*(m>>3) + (m&7) + 11;
          #pragma unroll
          for (int s=0;s<8;s++){
            bf16x8 A = *(const bf16x8*)&sm[YS + hrow*YSTR + s*32 + quad*8];
            a = MFMA(A, Bq[s], a);
          }
          #pragma unroll
          for (int r=0;r<4;r++){
            int row = mt*16 + quad*4 + r;
            sm[QS + row*HSTR + colB + n16] = (uint16_t)f2b(a[r] + bq);
          }
        }
      }
    }
    __syncthreads();
    // ---- phase 3: attention (waves 0-7, d-split) || chans (waves 8-15) ----
    if (wave < 8){
      int h = wave >> 1, ph = wave & 1;
      int pl = lane & 31, dh = lane >> 5;
      int p = ph*32 + pl;
      int iy = p >> 3, ix = p & 7;
      int co = h*32 + dh*16;
      u32x4 qa = *(const u32x4*)&sm[QS + p*HSTR + co];
      u32x4 qb = *(const u32x4*)&sm[QS + p*HSTR + co + 8];
      float qv[16];
      #pragma unroll
      for (int i=0;i<4;i++){
        qv[2*i]   = b2f(qa[i]);  qv[2*i+1]   = b2fh(qa[i]);
        qv[8+2*i] = b2f(qb[i]);  qv[8+2*i+1] = b2fh(qb[i]);
      }
      int hb = (iy+1)*10 + ix + 1;
      const int off[9] = {-11,-10,-9,-1,0,1,9,10,11};
      float sc[9];
      #pragma unroll
      for (int nb=0;nb<9;nb++){
        const uint16_t* kr = &sm[KS + (hb+off[nb])*HSTR + co];
        u32x4 ka = *(const u32x4*)kr;
        u32x4 kb = *(const u32x4*)(kr+8);
        float s = 0.f;
        #pragma unroll
        for (int i=0;i<4;i++){
          s += qv[2*i]*b2f(ka[i]) + qv[2*i+1]*b2fh(ka[i]);
          s += qv[8+2*i]*b2f(kb[i]) + qv[8+2*i+1]*b2fh(kb[i]);
        }
        sc[nb] = s;
      }
      #pragma unroll
      for (int nb=0;nb<9;nb++) sc[nb] = (sc[nb] + __shfl_xor(sc[nb], 32)) * 0.17677669529663687f;
      float mx = sc[0];
      #pragma unroll
      for (int nb=1;nb<9;nb++) mx = fmaxf(mx, sc[nb]);
      float l = 0.f;
      #pragma unroll
      for (int nb=0;nb<9;nb++){ sc[nb] = __expf(sc[nb]-mx); l += sc[nb]; }
      float inv = 1.f / l;
      float o[16];
      #pragma unroll
      for (int i=0;i<16;i++) o[i]=0.f;
      #pragma unroll
      for (int nb=0;nb<9;nb++){
        float wgt = sc[nb]*inv;
        const uint16_t* vr = &sm[VS + (hb+off[nb])*HSTR + co];
        u32x4 va = *(const u32x4*)vr;
        u32x4 vb = *(const u32x4*)(vr+8);
        #pragma unroll
        for (int i=0;i<4;i++){
          o[2*i]     += wgt*b2f(va[i]);  o[2*i+1]   += wgt*b2fh(va[i]);
          o[8+2*i]   += wgt*b2f(vb[i]);  o[8+2*i+1] += wgt*b2fh(vb[i]);
        }
      }
      #pragma unroll
      for (int i=0;i<8;i++) opk[hf][i] = f2b(o[2*i]) | (f2b(o[2*i+1])<<16);
    } else if (hf == 0){
      // chans GEMM -> registers (reads Y, N=256 over waves 8-15 x 2 ntg)
      #pragma unroll
      for (int jj=0;jj<2;jj++){
        int ntg = (wave-8)*2 + jj;
        bf16x8 Bc[8];
        #pragma unroll
        for (int s=0;s<8;s++) Bc[s] = *(const bf16x8*)&g_wpk[WCF + ((ntg*8+s)*64+lane)*8];
        float bc = bqkv[4*(ntg*16+n16) + 3];
        #pragma unroll
        for (int mt=0; mt<4; mt++){
          f32x4 a = {0.f,0.f,0.f,0.f};
          int m = mt*16 + n16;
          int hrow = 10*(m>>3) + (m&7) + 11;
          #pragma unroll
          for (int s=0;s<8;s++){
            bf16x8 A = *(const bf16x8*)&sm[YS + hrow*YSTR + s*32 + quad*8];
            a = MFMA(A, Bc[s], a);
          }
          chp[(jj*4+mt)*2+0] = f2b(a[0]+bc) | (f2b(a[1]+bc)<<16);
          chp[(jj*4+mt)*2+1] = f2b(a[2]+bc) | (f2b(a[3]+bc)<<16);
        }
      }
    } else {
      // hf=1: dump ch regs -> MCH (Y rows 0..63 dead now)
      #pragma unroll
      for (int jj=0;jj<2;jj++){
        int ntg = (wave-8)*2 + jj;
        int col = ntg*16 + n16;
        #pragma unroll
        for (int mt=0;mt<4;mt++){
          #pragma unroll
          for (int r2=0;r2<2;r2++){
            uint32_t v = chp[(jj*4+mt)*2+r2];
            int row = mt*16 + quad*4 + r2*2;
            sm[MCH + row*YSTR + col]        = (uint16_t)(v & 0xffffu);
            sm[MCH + (row+1)*YSTR + col]    = (uint16_t)(v >> 16);
          }
        }
      }
    }
    __syncthreads();
  }
  // ---- phase 4: attention dump -> MAO (waves 0-7) || W1 GEMM (waves 8-15) ----
  if (wave < 8){
    int h = wave >> 1, ph = wave & 1;
    int pl = lane & 31, dh = lane >> 5;
    int p = ph*32 + pl;
    int co = h*32 + dh*16;
    #pragma unroll
    for (int hf=0;hf<2;hf++){
      u32x4 s0 = {opk[hf][0],opk[hf][1],opk[hf][2],opk[hf][3]};
      u32x4 s1 = {opk[hf][4],opk[hf][5],opk[hf][6],opk[hf][7]};
      *(u32x4*)&sm[MAO + p*YSTR + hf*128 + co]     = s0;
      *(u32x4*)&sm[MAO + p*YSTR + hf*128 + co + 8] = s1;
    }
  } else {
    int ntg = wave - 8;
    bf16x8 Bf[8];
    #pragma unroll
    for (int s=0;s<8;s++) Bf[s] = *(const bf16x8*)&g_wpk[W1F + ((ntg*8+s)*64+lane)*8];
    float bs = b1[ntg*16+n16];
    int colB = ntg*16;
    #pragma unroll
    for (int mt=0;mt<4;mt++){
      f32x4 a = {0.f,0.f,0.f,0.f};
      #pragma unroll
      for (int s=0;s<8;s++){
        bf16x8 A = *(const bf16x8*)&sm[MCH + (mt*16+n16)*YSTR + s*32 + quad*8];
        a = MFMA(A, Bf[s], a);
      }
      #pragma unroll
      for (int r=0;r<4;r++){
        int row = mt*16 + quad*4 + r;
        sm[MHS + row*HSTR + colB + n16] = (uint16_t)f2b(fmaxf(a[r]+bs, 0.f));
      }
    }
  }
  __syncthreads();
  // ---- phase 5: g = sigmoid(h@W2^T+b2); t = ao*(1+g) -> MCH ----
  {
    int ntg = wave;
    bf16x8 Bf[4];
    #pragma unroll
    for (int s=0;s<4;s++) Bf[s] = *(const bf16x8*)&g_wpk[W2F + ((ntg*4+s)*64+lane)*8];
    float bs = b2v[ntg*16+n16];
    int colB = ntg*16;
    #pragma unroll
    for (int mt=0;mt<4;mt++){
      f32x4 a = {0.f,0.f,0.f,0.f};
      #pragma unroll
      for (int s=0;s<4;s++){
        bf16x8 A = *(const bf16x8*)&sm[MHS + (mt*16+n16)*HSTR + s*32 + quad*8];
        a = MFMA(A, Bf[s], a);
      }
      #pragma unroll
      for (int r=0;r<4;r++){
        int row = mt*16 + quad*4 + r;
        float gg = 1.f/(1.f+__expf(-(a[r] + bs)));
        float ao = b2f((uint32_t)sm[MAO + row*YSTR + colB + n16]);
        sm[MCH + row*YSTR + colB + n16] = (uint16_t)f2b(ao*(1.f+gg));
      }
    }
  }
  __syncthreads();
  // ---- phase 6: out_t = t @ Wp^T + bp -> MAO ----
  {
    int ntg = wave;
    bf16x8 Bf[8];
    #pragma unroll
    for (int s=0;s<8;s++) Bf[s] = *(const bf16x8*)&g_wpk[WPF + ((ntg*8+s)*64+lane)*8];
    float bs = bp[ntg*16+n16];
    int colB = ntg*16;
    #pragma unroll
    for (int mt=0;mt<4;mt++){
      f32x4 a = {0.f,0.f,0.f,0.f};
      #pragma unroll
      for (int s=0;s<8;s++){
        bf16x8 A = *(const bf16x8*)&sm[MCH + (mt*16+n16)*YSTR + s*32 + quad*8];
        a = MFMA(A, Bf[s], a);
      }
      #pragma unroll
      for (int r=0;r<4;r++){
        int row = mt*16 + quad*4 + r;
        sm[MAO + row*YSTR + colB + n16] = (uint16_t)f2b(a[r]+bs);
      }
    }
  }
  __syncthreads();
  // ---- phase 7: fp32 NCHW write ----
  #pragma unroll
  for (int i=0;i<4;i++){
    int idx = t + 1024*i;               // 4096 tasks
    int ix4 = idx&1, iy = (idx>>1)&7, c = idx>>4;
    f32x4 stv;
    #pragma unroll
    for (int j=0;j<4;j++){
      int p = iy*8 + ix4*4 + j;
      stv[j] = b2f((uint32_t)sm[MAO + p*YSTR + c]);
    }
    *(f32x4*)&out[(((bb*256+c)*64) + ty*8+iy)*64 + tx*8 + ix4*4] = stv;
  }
}

extern "C" void kernel_launch(void* const* d_in, const int* in_sizes, int n_in,
                              void* d_out, int out_size, void* d_ws, size_t ws_size,
                              hipStream_t stream){
  (void)in_sizes; (void)n_in; (void)d_ws; (void)ws_size; (void)out_size;
  const float* x    = (const float*)d_in[0];
  const float* Wqkv = (const float*)d_in[1];
  const float* bqkv = (const float*)d_in[2];
  const float* W1   = (const float*)d_in[3];
  const float* b1   = (const float*)d_in[4];
  const float* W2   = (const float*)d_in[5];
  const float* b2   = (const float*)d_in[6];
  const float* Wp   = (const float*)d_in[7];
  const float* bp   = (const float*)d_in[8];
  kpack<<<dim3(1536), dim3(256), 0, stream>>>(Wqkv, W1, W2, Wp);
  kpool<<<dim3(512),  dim3(512), 0, stream>>>(x);
  kattn<<<dim3(512),  dim3(1024), 0, stream>>>(bqkv, b1, b2, bp, (float*)d_out);
}